// Round 5
// baseline (452.190 us; speedup 1.0000x reference)
//
#include <hip/hip_runtime.h>

// ---------------------------------------------------------------------------
// SelfAttentionDecoder: out = (softmax(mask((qWq^T+bq)(xWk^T+bk)^T/8)) (xWv^T+bv)) Wo^T + bo
// B=16, N1=N2=1024, D=1024, H=16, DH=64.
// Round 9: GEMM -> 256x256 tile, 8 waves (512 thr), BK=64, counted-vmcnt
// pipeline (T3+T4): raw s_barrier, s_waitcnt vmcnt(8) (never 0 in loop),
// wave-specialized staging (each wave gll-stages exactly the A-half/B-half it
// consumes -> per-wave vmcnt accounting is exact). LDS 128KB, 1 blk/CU,
// grid 256 = one round. Attn reverted to R7 exact (pad removed).
// ---------------------------------------------------------------------------

typedef float f32x4 __attribute__((ext_vector_type(4)));
typedef float f32x16 __attribute__((ext_vector_type(16)));
typedef __bf16 bf16x8 __attribute__((ext_vector_type(8)));

// 0.125 * log2(e): QK^T scores arrive pre-scaled for exp2-based softmax.
#define QSCALE 0.18033688f

__device__ __forceinline__ unsigned short f2bf(float f) {
    unsigned u = __builtin_bit_cast(unsigned, f);
    unsigned r = u + 0x7fffu + ((u >> 16) & 1u);   // RNE
    return (unsigned short)(r >> 16);
}
__device__ __forceinline__ unsigned pk2(float a, float b) {
    return (unsigned)f2bf(a) | ((unsigned)f2bf(b) << 16);
}

// ---------------------------------------------------------------------------
// fp32 -> bf16 converters. cvt_bf16: y-dim selects (q, x) source.
// ---------------------------------------------------------------------------
__global__ __launch_bounds__(256) void cvt_bf16(const float* __restrict__ s0,
                                                unsigned short* __restrict__ d0,
                                                const float* __restrict__ s1,
                                                unsigned short* __restrict__ d1) {
    const float* src = blockIdx.y ? s1 : s0;
    unsigned short* dst = blockIdx.y ? d1 : d0;
    const int idx = blockIdx.x * 256 + threadIdx.x;
    float4 a = ((const float4*)src)[idx * 2];
    float4 b = ((const float4*)src)[idx * 2 + 1];
    uint4 u;
    u.x = pk2(a.x, a.y); u.y = pk2(a.z, a.w);
    u.z = pk2(b.x, b.y); u.w = pk2(b.z, b.w);
    ((uint4*)dst)[idx] = u;
}

__global__ __launch_bounds__(256) void cvt_w4(const float* __restrict__ W0,
                                              const float* __restrict__ W1,
                                              const float* __restrict__ W2,
                                              const float* __restrict__ W3,
                                              unsigned short* __restrict__ o0,
                                              unsigned short* __restrict__ o1,
                                              unsigned short* __restrict__ o2,
                                              unsigned short* __restrict__ o3) {
    const float* s = (blockIdx.y == 0) ? W0 : (blockIdx.y == 1) ? W1
                   : (blockIdx.y == 2) ? W2 : W3;
    unsigned short* d = (blockIdx.y == 0) ? o0 : (blockIdx.y == 1) ? o1
                      : (blockIdx.y == 2) ? o2 : o3;
    const int idx = blockIdx.x * 256 + threadIdx.x;   // 131072 chunks of 8
    float4 a = ((const float4*)s)[idx * 2];
    float4 b = ((const float4*)s)[idx * 2 + 1];
    uint4 u;
    u.x = pk2(a.x, a.y); u.y = pk2(a.z, a.w);
    u.z = pk2(b.x, b.y); u.w = pk2(b.z, b.w);
    ((uint4*)d)[idx] = u;
}

// ---------------------------------------------------------------------------
// GEMM 256x256 counted-vmcnt: C[M,N] = (A[M,K] @ W[N,K]^T + bias)*scale.
// M=16384 N=1024 K=1024. 8 waves (2M x 4N), per-wave 128x64 out (8x4 frags
// of 16x16). LDS: As[2][256x64] + Bs[2][256x64] = 128KB, 1 blk/CU, grid 256.
//
// Wave-specialized staging (per K-tile, 8 gll-16B per wave):
//   A-half rh=w>>2 staged by the 4 waves sharing rh (wl=w&3, 4 instr each);
//   B-half bh=(w>>1)&1 staged by the 4 waves sharing bh (bl, 4 instr each).
//   LDS dest = uniform + lane*16 (gll constraint); XOR swizzle applied on the
//   GLOBAL source chunk (csrc = pos ^ (row&7)) as in R4-R8.
// K-loop (per iter t): issue STAGE(t+1) -> s_waitcnt vmcnt(8) (stage t done,
// stage t+1 in flight) -> s_barrier -> ds_read+MFMA on buf[t&1] ->
// lgkmcnt(0) -> s_barrier. Stage(t) gets a FULL iteration of slack.
// OUTM: 0 = bf16 row-major; 1 = fp32 row-major; 2 = bf16 V^T [b][h][dh][n2].
// ---------------------------------------------------------------------------
template <int OUTM>
__global__ __launch_bounds__(512, 2) void gemm256(const unsigned short* __restrict__ A,
                                                  const unsigned short* __restrict__ W,
                                                  const float* __restrict__ bias,
                                                  void* __restrict__ Cp,
                                                  float scale) {
    constexpr int N = 1024, K = 1024;
    __shared__ unsigned short As[2][256 * 64];
    __shared__ unsigned short Bs[2][256 * 64];

    const int t    = threadIdx.x;
    const int wave = t >> 6;          // 0..7
    const int lane = t & 63;
    const int lm   = lane & 15;
    const int quad = lane >> 4;

    // XCD map: each XCD owns one B n-panel (L2-resident) and streams A.
    const int bid = blockIdx.x;       // 0..255
    const int xcd = bid & 7;
    const int jj  = bid >> 3;         // 0..31
    const int n0  = (xcd & 3) * 256;
    const int m0  = ((xcd >> 2) * 32 + jj) * 256;

    const int wr = (wave >> 2) * 128;     // wave's A row-half base (0/128)
    const int wc = (wave & 3) * 64;       // wave's B col base (0..192)

    // staging assignments
    const int rh = wave >> 2;                       // A-half this wave stages
    const int wl = wave & 3;                        // index within A-half stagers
    const int bh = (wave >> 1) & 1;                 // B-half this wave stages
    const int bl = (wave & 1) | ((wave >> 2) << 1); // index within B-half stagers

    int aoff[4], aldo[4], boff[4], bldo[4];
#pragma unroll
    for (int i = 0; i < 4; i++) {
        {
            const int slot = (wl * 4 + i) * 64 + lane;   // 0..1023 within half
            const int r    = slot >> 3;                  // row 0..127
            const int csrc = (slot & 7) ^ (r & 7);
            aoff[i] = (m0 + rh * 128 + r) * K + csrc * 8;
            aldo[i] = rh * 16384 + slot * 16;            // byte offset in As[cb]
        }
        {
            const int slot = (bl * 4 + i) * 64 + lane;
            const int r    = slot >> 3;
            const int csrc = (slot & 7) ^ (r & 7);
            boff[i] = (n0 + bh * 128 + r) * K + csrc * 8;
            bldo[i] = bh * 16384 + slot * 16;
        }
    }

    auto STAGE = [&](int cb, int k0) {
#pragma unroll
        for (int i = 0; i < 4; i++) {
            __builtin_amdgcn_global_load_lds(
                (const __attribute__((address_space(1))) unsigned int*)(A + aoff[i] + k0),
                (__attribute__((address_space(3))) unsigned int*)((char*)&As[cb][0] + aldo[i]),
                16, 0, 0);
            __builtin_amdgcn_global_load_lds(
                (const __attribute__((address_space(1))) unsigned int*)(W + boff[i] + k0),
                (__attribute__((address_space(3))) unsigned int*)((char*)&Bs[cb][0] + bldo[i]),
                16, 0, 0);
        }
    };

    f32x4 acc[8][4] = {};

    STAGE(0, 0);

    int cur = 0;
    for (int kt = 0; kt < 16; ++kt) {
        if (kt < 15) {
            STAGE(cur ^ 1, (kt + 1) * 64);
            asm volatile("s_waitcnt vmcnt(8)" ::: "memory");   // stage(kt) landed
        } else {
            asm volatile("s_waitcnt vmcnt(0)" ::: "memory");
        }
        __builtin_amdgcn_s_barrier();          // all waves' halves complete
        __builtin_amdgcn_sched_barrier(0);

        // B fragments (reused by both row-groups)
        bf16x8 bfr[4][2];
#pragma unroll
        for (int j = 0; j < 4; j++)
#pragma unroll
            for (int ks = 0; ks < 2; ks++) {
                const int row = wc + j * 16 + lm;
                const int pos = ((ks * 4 + quad) ^ (row & 7)) * 16;
                bfr[j][ks] = *(const bf16x8*)((const char*)&Bs[cur][0] + row * 128 + pos);
            }
#pragma unroll
        for (int ih = 0; ih < 2; ih++) {
            bf16x8 af[4][2];
#pragma unroll
            for (int i4 = 0; i4 < 4; i4++)
#pragma unroll
                for (int ks = 0; ks < 2; ks++) {
                    const int row = wr + ih * 64 + i4 * 16 + lm;
                    const int pos = ((ks * 4 + quad) ^ (row & 7)) * 16;
                    af[i4][ks] = *(const bf16x8*)((const char*)&As[cur][0] + row * 128 + pos);
                }
            __builtin_amdgcn_s_setprio(1);
#pragma unroll
            for (int ks = 0; ks < 2; ks++)
#pragma unroll
                for (int i4 = 0; i4 < 4; i4++)
#pragma unroll
                    for (int j = 0; j < 4; j++)
                        acc[ih * 4 + i4][j] = __builtin_amdgcn_mfma_f32_16x16x32_bf16(
                            af[i4][ks], bfr[j][ks], acc[ih * 4 + i4][j], 0, 0, 0);
            __builtin_amdgcn_s_setprio(0);
        }

        asm volatile("s_waitcnt lgkmcnt(0)" ::: "memory");  // ds_reads complete
        __builtin_amdgcn_s_barrier();          // safe to overwrite buf next iter
        cur ^= 1;
    }

    // ---- epilogue ----
#pragma unroll
    for (int i = 0; i < 8; i++) {
        const int row = m0 + wr + i * 16 + quad * 4;
#pragma unroll
        for (int j = 0; j < 4; j++) {
            const int col = n0 + wc + j * 16 + lm;
            const float bb = bias[col];
            if constexpr (OUTM == 2) {
                const int bi = row >> 10, n2 = row & 1023;
                const int hh = col >> 6, dh = col & 63;
                uint2 pkd;
                pkd.x = pk2((acc[i][j][0] + bb) * scale, (acc[i][j][1] + bb) * scale);
                pkd.y = pk2((acc[i][j][2] + bb) * scale, (acc[i][j][3] + bb) * scale);
                *(uint2*)&((unsigned short*)Cp)[((size_t)((bi * 16 + hh) * 64 + dh) << 10) + n2] = pkd;
            } else {
#pragma unroll
                for (int rr = 0; rr < 4; rr++) {
                    const float v = (acc[i][j][rr] + bb) * scale;
                    if constexpr (OUTM == 0)
                        ((unsigned short*)Cp)[(size_t)(row + rr) * N + col] = f2bf(v);
                    else
                        ((float*)Cp)[(size_t)(row + rr) * N + col] = v;
                }
            }
        }
    }
}

// ---------------------------------------------------------------------------
// Fallback GEMM (fp32 inputs, conversion in staging) — minimal-ws path only.
// ---------------------------------------------------------------------------
template <bool A_BF16, int OUTM>
__global__ __launch_bounds__(256) void gemm_bt(const void* __restrict__ Ap,
                                               const float* __restrict__ Wp,
                                               const float* __restrict__ bias,
                                               void* __restrict__ Cp,
                                               float scale) {
    constexpr int N = 1024, K = 1024;
    __shared__ unsigned short As[128 * 40];
    __shared__ unsigned short Bs[128 * 40];

    const int t    = threadIdx.x;
    const int n0   = blockIdx.x * 128;
    const int m0   = blockIdx.y * 128;
    const int wave = t >> 6;
    const int lane = t & 63;
    const int wr   = (wave >> 1) * 64;
    const int wc   = (wave & 1) * 64;
    const int lm   = lane & 15;
    const int quad = lane >> 4;
    const int kfr  = quad * 8;
    const int srow  = t >> 1;
    const int shalf = (t & 1) * 16;

    f32x4 acc[4][4] = {};

    for (int k0 = 0; k0 < K; k0 += 32) {
        {
            unsigned short* dst = &As[srow * 40 + shalf];
            if constexpr (A_BF16) {
                const unsigned short* pa =
                    (const unsigned short*)Ap + (size_t)(m0 + srow) * K + k0 + shalf;
                *(uint4*)dst       = *(const uint4*)pa;
                *(uint4*)(dst + 8) = *(const uint4*)(pa + 8);
            } else {
                const float* pa = (const float*)Ap + (size_t)(m0 + srow) * K + k0 + shalf;
                float4 f0 = *(const float4*)(pa + 0);
                float4 f1 = *(const float4*)(pa + 4);
                float4 f2 = *(const float4*)(pa + 8);
                float4 f3 = *(const float4*)(pa + 12);
                uint4 u0, u1;
                u0.x = pk2(f0.x, f0.y); u0.y = pk2(f0.z, f0.w);
                u0.z = pk2(f1.x, f1.y); u0.w = pk2(f1.z, f1.w);
                u1.x = pk2(f2.x, f2.y); u1.y = pk2(f2.z, f2.w);
                u1.z = pk2(f3.x, f3.y); u1.w = pk2(f3.z, f3.w);
                *(uint4*)dst       = u0;
                *(uint4*)(dst + 8) = u1;
            }
        }
        {
            const float* pb = Wp + (size_t)(n0 + srow) * K + k0 + shalf;
            float4 f0 = *(const float4*)(pb + 0);
            float4 f1 = *(const float4*)(pb + 4);
            float4 f2 = *(const float4*)(pb + 8);
            float4 f3 = *(const float4*)(pb + 12);
            uint4 u0, u1;
            u0.x = pk2(f0.x, f0.y); u0.y = pk2(f0.z, f0.w);
            u0.z = pk2(f1.x, f1.y); u0.w = pk2(f1.z, f1.w);
            u1.x = pk2(f2.x, f2.y); u1.y = pk2(f2.z, f2.w);
            u1.z = pk2(f3.x, f3.y); u1.w = pk2(f3.z, f3.w);
            unsigned short* dst = &Bs[srow * 40 + shalf];
            *(uint4*)dst       = u0;
            *(uint4*)(dst + 8) = u1;
        }
        __syncthreads();

        bf16x8 af[4], bfr[4];
#pragma unroll
        for (int i = 0; i < 4; i++)
            af[i] = *reinterpret_cast<const bf16x8*>(&As[(wr + i * 16 + lm) * 40 + kfr]);
#pragma unroll
        for (int j = 0; j < 4; j++)
            bfr[j] = *reinterpret_cast<const bf16x8*>(&Bs[(wc + j * 16 + lm) * 40 + kfr]);
#pragma unroll
        for (int i = 0; i < 4; i++)
#pragma unroll
            for (int j = 0; j < 4; j++)
                acc[i][j] = __builtin_amdgcn_mfma_f32_16x16x32_bf16(af[i], bfr[j],
                                                                    acc[i][j], 0, 0, 0);
        __syncthreads();
    }

#pragma unroll
    for (int i = 0; i < 4; i++) {
        const int row = m0 + wr + i * 16 + quad * 4;
#pragma unroll
        for (int j = 0; j < 4; j++) {
            const int col = n0 + wc + j * 16 + lm;
            const float bb = bias[col];
#pragma unroll
            for (int rr = 0; rr < 4; rr++) {
                const float v = (acc[i][j][rr] + bb) * scale;
                const int m = row + rr;
                if constexpr (OUTM == 0) {
                    ((unsigned short*)Cp)[(size_t)m * N + col] = f2bf(v);
                } else if constexpr (OUTM == 1) {
                    ((float*)Cp)[(size_t)m * N + col] = v;
                } else {
                    const int bi = m >> 10, n2 = m & 1023;
                    const int hh = col >> 6, dh = col & 63;
                    ((unsigned short*)Cp)[((size_t)((bi * 16 + hh) * 64 + dh) << 10) + n2] =
                        f2bf(v);
                }
            }
        }
    }
}

// ---------------------------------------------------------------------------
// Pack adj (int32 0/1, [1024][1024]) into bitmask [1024][32] words.
// ---------------------------------------------------------------------------
__global__ __launch_bounds__(256) void pack_adj(const int* __restrict__ adj,
                                                unsigned* __restrict__ adjm) {
    const int idx = blockIdx.x * 256 + threadIdx.x;  // 0..32767
    const int* src = adj + (size_t)idx * 32;
    unsigned w = 0;
#pragma unroll
    for (int i = 0; i < 32; i++) w |= (src[i] != 0 ? 1u : 0u) << i;
    adjm[idx] = w;
}

// ---------------------------------------------------------------------------
// MFMA flash attention, 32x32x16 shape, swapped QK^T, in-register softmax.
// 1D grid 2048 (XCD-swizzled), 4 waves x 32 q-rows = 128 q per block. (R7)
// ---------------------------------------------------------------------------
__global__ __launch_bounds__(256, 3) void attn_kernel(const unsigned short* __restrict__ Q,
                                                      const unsigned short* __restrict__ K,
                                                      const unsigned short* __restrict__ Vt,
                                                      const unsigned* __restrict__ adjm,
                                                      unsigned short* __restrict__ O) {
    __shared__ unsigned short Kbuf[2][4096];   // [kv 0..63][8-chunk pos 0..7]
    __shared__ unsigned short Vbuf[2][4096];   // [dh 0..63][pos]

    const int t    = threadIdx.x;
    const int wave = t >> 6;
    const int lane = t & 63;
    const int l32  = lane & 31;
    const int hi   = lane >> 5;

    const int bid   = blockIdx.x;
    const int xcd   = bid & 7;
    const int jj    = bid >> 3;               // 0..255
    const int group = xcd * 32 + (jj >> 3);   // 0..255 = b*16+h
    const int q0    = (jj & 7) * 128;
    const int h     = group & 15;
    const int b     = group >> 4;

    const int qrow = q0 + wave * 32 + l32;    // this lane's q row

    int    ldofs[2];
    size_t kofs[2], vofs[2];
#pragma unroll
    for (int i = 0; i < 2; i++) {
        const int slot = i * 256 + t;
        const int r    = slot >> 3;
        const int cs   = (slot & 7) ^ (r & 7);
        ldofs[i] = slot * 16;
        kofs[i]  = (size_t)(b * 1024 + r) * 1024 + h * 64 + cs * 8;   // + j0*1024
        vofs[i]  = ((size_t)((b * 16 + h) * 64 + r) << 10) + cs * 8;  // + j0
    }

    // Q B-frags: aq[s] covers dh = s*16 + hi*8 .. +8 for col q = l32.
    bf16x8 aq[4];
    {
        const unsigned short* qp =
            Q + ((size_t)(b * 1024 + qrow) * 1024 + h * 64 + hi * 8);
#pragma unroll
        for (int s = 0; s < 4; s++)
            aq[s] = __builtin_bit_cast(bf16x8, *(const uint4*)(qp + s * 16));
    }

    bf16x8 bones;
    {
        uint4 u; u.x = 0x3F803F80u; u.y = u.x; u.z = u.x; u.w = u.x;
        bones = __builtin_bit_cast(bf16x8, u);   // all-ones B fragment
    }

    f32x16 of0 = {}, of1 = {}, ol = {};

    auto STAGE = [&](int bi, int c) {
        const size_t j0 = (size_t)c * 64;
#pragma unroll
        for (int i = 0; i < 2; i++) {
            __builtin_amdgcn_global_load_lds(
                (const __attribute__((address_space(1))) unsigned int*)(K + kofs[i] + j0 * 1024),
                (__attribute__((address_space(3))) unsigned int*)((char*)&Kbuf[bi][0] + ldofs[i]),
                16, 0, 0);
            __builtin_amdgcn_global_load_lds(
                (const __attribute__((address_space(1))) unsigned int*)(Vt + vofs[i] + j0),
                (__attribute__((address_space(3))) unsigned int*)((char*)&Vbuf[bi][0] + ldofs[i]),
                16, 0, 0);
        }
    };

    STAGE(0, 0);
    __syncthreads();   // vmcnt(0) drain: buf0 ready

    int bi = 0;
    for (int c = 0; c < 16; ++c) {
        const uint2 mw = *(const uint2*)&adjm[(size_t)qrow * 32 + c * 2];

        if (c < 15) STAGE(bi ^ 1, c + 1);

        // --- QK^T (swapped): sf[f] over dh steps ---
        f32x16 sf[2] = {{}, {}};
        __builtin_amdgcn_s_setprio(1);
#pragma unroll
        for (int f = 0; f < 2; f++)
#pragma unroll
            for (int s = 0; s < 4; s++) {
                const int pos = ((2 * s + hi) ^ (l32 & 7)) * 16;
                const bf16x8 kf =
                    *(const bf16x8*)((const char*)&Kbuf[bi][0] + (f * 32 + l32) * 128 + pos);
                sf[f] = __builtin_amdgcn_mfma_f32_32x32x16_bf16(kf, aq[s], sf[f], 0, 0, 0);
            }
        __builtin_amdgcn_s_setprio(0);

        // --- mask + exp2 + pack to bf16 pairs (in registers) ---
        unsigned d[2][4][2];
#pragma unroll
        for (int f = 0; f < 2; f++) {
            const unsigned wh = ((f == 0) ? mw.x : mw.y) >> (hi * 4);
            float p[16];
#pragma unroll
            for (int r = 0; r < 16; r++) {
                const unsigned bit = (wh >> ((r & 3) + 8 * (r >> 2))) & 1u;
                p[r] = __builtin_amdgcn_exp2f(bit ? sf[f][r] : -1e30f);
            }
#pragma unroll
            for (int a = 0; a < 4; a++)
#pragma unroll
                for (int bb = 0; bb < 2; bb++) {
                    unsigned dd;
                    asm("v_cvt_pk_bf16_f32 %0, %1, %2"
                        : "=v"(dd) : "v"(p[4 * a + 2 * bb]), "v"(p[4 * a + 2 * bb + 1]));
                    d[f][a][bb] = dd;
                }
        }

        // --- redistribute halves: build PV A-frags tA[s] (kv = s*16+hi*8+j) ---
        bf16x8 tA[4];
#pragma unroll
        for (int s = 0; s < 4; s++) {
            const int f = s >> 1, sg = s & 1;
            unsigned A0 = d[f][2 * sg][0], B0 = d[f][2 * sg + 1][0];
            unsigned A1 = d[f][2 * sg][1], B1 = d[f][2 * sg + 1][1];
            asm("v_permlane32_swap_b32 %0, %1" : "+v"(A0), "+v"(B0));
            asm("v_permlane32_swap_b32 %0, %1" : "+v"(A1), "+v"(B1));
            uint4 td; td.x = A0; td.y = A1; td.z = B0; td.w = B1;
            tA[s] = __builtin_bit_cast(bf16x8, td);
        }

        // --- PV + row-sum ---
        __builtin_amdgcn_s_setprio(1);
#pragma unroll
        for (int s = 0; s < 4; s++) {
            const int pos = ((2 * s + hi) ^ (l32 & 7)) * 16;
            const bf16x8 v0 = *(const bf16x8*)((const char*)&Vbuf[bi][0] + l32 * 128 + pos);
            const bf16x8 v1 = *(const bf16x8*)((const char*)&Vbuf[bi][0] + (32 + l32) * 128 + pos);
            of0 = __builtin_amdgcn_mfma_f32_32x32x16_bf16(tA[s], v0, of0, 0, 0, 0);
            of1 = __builtin_amdgcn_mfma_f32_32x32x16_bf16(tA[s], v1, of1, 0, 0, 0);
            ol  = __builtin_amdgcn_mfma_f32_32x32x16_bf16(tA[s], bones, ol, 0, 0, 0);
        }
        __builtin_amdgcn_s_setprio(0);

        __syncthreads();   // drain: next buf staged + all waves done reading bi
        bi ^= 1;
    }

    // --- normalize + store: lane holds q rows crow(r,hi), d = e*32 + l32 ---
#pragma unroll
    for (int r = 0; r < 16; r++) {
        const float iv = 1.0f / ol[r];
        const size_t row = (size_t)(b * 1024 + q0 + wave * 32 +
                                    (r & 3) + 8 * (r >> 2) + 4 * hi);
        unsigned short* op = O + row * 1024 + h * 64 + l32;
        op[0]  = f2bf(of0[r] * iv);
        op[32] = f2bf(of1[r] * iv);
    }
}

// ---------------------------------------------------------------------------
extern "C" void kernel_launch(void* const* d_in, const int* in_sizes, int n_in,
                              void* d_out, int out_size, void* d_ws, size_t ws_size,
                              hipStream_t stream) {
    const float* q  = (const float*)d_in[0];
    const float* x  = (const float*)d_in[1];
    const float* Wq = (const float*)d_in[2];
    const float* bq = (const float*)d_in[3];
    const float* Wk = (const float*)d_in[4];
    const float* bk = (const float*)d_in[5];
    const float* Wv = (const float*)d_in[6];
    const float* bv = (const float*)d_in[7];
    const float* Wo = (const float*)d_in[8];
    const float* bo = (const float*)d_in[9];
    const int* adj  = (const int*)d_in[10];
    float* out = (float*)d_out;

    const size_t MB = 1024 * 1024;
    char* w = (char*)d_ws;

    dim3 g256(256), tb(256), tb512(512);
    const size_t FULL_WS = 168 * MB + 128 * 1024;

    if (ws_size >= FULL_WS) {
        unsigned short* qb  = (unsigned short*)(w);
        unsigned short* xb  = (unsigned short*)(w + 32 * MB);
        unsigned short* Wqb = (unsigned short*)(w + 64 * MB);
        unsigned short* Wkb = (unsigned short*)(w + 66 * MB);
        unsigned short* Wvb = (unsigned short*)(w + 68 * MB);
        unsigned short* Wob = (unsigned short*)(w + 70 * MB);
        unsigned short* Qb  = (unsigned short*)(w + 72 * MB);
        unsigned short* Kb  = (unsigned short*)(w + 104 * MB);
        unsigned short* Vtb = (unsigned short*)(w + 136 * MB);
        unsigned* adjm      = (unsigned*)(w + 168 * MB);
        unsigned short* Ob  = qb;  // qb dead after Q-GEMM

        hipLaunchKernelGGL(cvt_bf16, dim3(8192, 2), tb, 0, stream, q, qb, x, xb);
        hipLaunchKernelGGL(cvt_w4, dim3(512, 4), tb, 0, stream, Wq, Wk, Wv, Wo,
                           Wqb, Wkb, Wvb, Wob);
        hipLaunchKernelGGL(pack_adj, dim3(128), tb, 0, stream, adj, adjm);

        hipLaunchKernelGGL((gemm256<0>), g256, tb512, 0, stream, qb, Wqb, bq, (void*)Qb, QSCALE);
        hipLaunchKernelGGL((gemm256<0>), g256, tb512, 0, stream, xb, Wkb, bk, (void*)Kb, 1.0f);
        hipLaunchKernelGGL((gemm256<2>), g256, tb512, 0, stream, xb, Wvb, bv, (void*)Vtb, 1.0f);
        hipLaunchKernelGGL(attn_kernel, dim3(2048), tb, 0, stream, Qb, Kb, Vtb, adjm, Ob);
        hipLaunchKernelGGL((gemm256<1>), g256, tb512, 0, stream, Ob, Wob, bo, (void*)out, 1.0f);
    } else {
        // minimal path (134.1 MB): convert in GEMM staging
        unsigned short* Qb  = (unsigned short*)(w);
        unsigned short* Kb  = (unsigned short*)(w + 32 * MB);
        unsigned short* Vtb = (unsigned short*)(w + 64 * MB);
        unsigned short* Ob  = (unsigned short*)(w + 96 * MB);
        unsigned* adjm      = (unsigned*)(w + 128 * MB);

        hipLaunchKernelGGL(pack_adj, dim3(128), tb, 0, stream, adj, adjm);
        hipLaunchKernelGGL((gemm_bt<false, 0>), dim3(8, 128), tb, 0, stream,
                           (const void*)q, Wq, bq, (void*)Qb, QSCALE);
        hipLaunchKernelGGL((gemm_bt<false, 0>), dim3(8, 128), tb, 0, stream,
                           (const void*)x, Wk, bk, (void*)Kb, 1.0f);
        hipLaunchKernelGGL((gemm_bt<false, 2>), dim3(8, 128), tb, 0, stream,
                           (const void*)x, Wv, bv, (void*)Vtb, 1.0f);
        hipLaunchKernelGGL(attn_kernel, dim3(2048), tb, 0, stream, Qb, Kb, Vtb, adjm, Ob);
        hipLaunchKernelGGL((gemm_bt<true, 1>), dim3(8, 128), tb, 0, stream,
                           (const void*)Ob, Wo, bo, (void*)out, 1.0f);
    }
}

// Round 6
// 449.667 us; speedup vs baseline: 1.0056x; 1.0056x over previous
//
#include <hip/hip_runtime.h>

// ---------------------------------------------------------------------------
// SelfAttentionDecoder: out = (softmax(mask((qWq^T+bq)(xWk^T+bk)^T/8)) (xWv^T+bv)) Wo^T + bo
// B=16, N1=N2=1024, D=1024, H=16, DH=64.
// Round 10: fuse Q/K/V GEMMs into ONE dispatch (grid 3072; z=bid>>10 selects
// A/W/bias/out/scale/epilogue — wave-uniform). Inside = R8 gemm2 structure
// (128x128, BK=64 dbuf, gll-16B XOR-swizzled staging, correct XCD map:
// 8 n-blocks of an m-panel share one XCD) + setprio around MFMA.
// Purpose: perf (2 fewer launches, ramp overlap) + observability (the fused
// ~220us dispatch will surface GEMM counters in the top-5 next round).
// O-proj = gemm2<1>; attn = R7 exact (112us).
// ---------------------------------------------------------------------------

typedef float f32x4 __attribute__((ext_vector_type(4)));
typedef float f32x16 __attribute__((ext_vector_type(16)));
typedef __bf16 bf16x8 __attribute__((ext_vector_type(8)));

// 0.125 * log2(e): QK^T scores arrive pre-scaled for exp2-based softmax.
#define QSCALE 0.18033688f

__device__ __forceinline__ unsigned short f2bf(float f) {
    unsigned u = __builtin_bit_cast(unsigned, f);
    unsigned r = u + 0x7fffu + ((u >> 16) & 1u);   // RNE
    return (unsigned short)(r >> 16);
}
__device__ __forceinline__ unsigned pk2(float a, float b) {
    return (unsigned)f2bf(a) | ((unsigned)f2bf(b) << 16);
}

// ---------------------------------------------------------------------------
// fp32 -> bf16 converters. cvt_bf16: y-dim selects (q, x) source.
// ---------------------------------------------------------------------------
__global__ __launch_bounds__(256) void cvt_bf16(const float* __restrict__ s0,
                                                unsigned short* __restrict__ d0,
                                                const float* __restrict__ s1,
                                                unsigned short* __restrict__ d1) {
    const float* src = blockIdx.y ? s1 : s0;
    unsigned short* dst = blockIdx.y ? d1 : d0;
    const int idx = blockIdx.x * 256 + threadIdx.x;
    float4 a = ((const float4*)src)[idx * 2];
    float4 b = ((const float4*)src)[idx * 2 + 1];
    uint4 u;
    u.x = pk2(a.x, a.y); u.y = pk2(a.z, a.w);
    u.z = pk2(b.x, b.y); u.w = pk2(b.z, b.w);
    ((uint4*)dst)[idx] = u;
}

__global__ __launch_bounds__(256) void cvt_w4(const float* __restrict__ W0,
                                              const float* __restrict__ W1,
                                              const float* __restrict__ W2,
                                              const float* __restrict__ W3,
                                              unsigned short* __restrict__ o0,
                                              unsigned short* __restrict__ o1,
                                              unsigned short* __restrict__ o2,
                                              unsigned short* __restrict__ o3) {
    const float* s = (blockIdx.y == 0) ? W0 : (blockIdx.y == 1) ? W1
                   : (blockIdx.y == 2) ? W2 : W3;
    unsigned short* d = (blockIdx.y == 0) ? o0 : (blockIdx.y == 1) ? o1
                      : (blockIdx.y == 2) ? o2 : o3;
    const int idx = blockIdx.x * 256 + threadIdx.x;   // 131072 chunks of 8
    float4 a = ((const float4*)s)[idx * 2];
    float4 b = ((const float4*)s)[idx * 2 + 1];
    uint4 u;
    u.x = pk2(a.x, a.y); u.y = pk2(a.z, a.w);
    u.z = pk2(b.x, b.y); u.w = pk2(b.z, b.w);
    ((uint4*)d)[idx] = u;
}

// ---------------------------------------------------------------------------
// Shared GEMM body (R8 gemm2 structure): 128x128 tile, BK=64 double-buffered,
// 256 thr (4 waves 2x2). OUTM: 0 bf16 row-major, 1 fp32, 2 bf16 V^T.
// ---------------------------------------------------------------------------
template <int OUTM_CONST>  // -1 = runtime outm
__device__ __forceinline__ void gemm_body(const unsigned short* __restrict__ A,
                                          const unsigned short* __restrict__ W,
                                          const float* __restrict__ bias,
                                          void* __restrict__ Cp,
                                          float scale, int b2, int outm_rt) {
    constexpr int N = 1024, K = 1024;
    __shared__ unsigned short As[2][128 * 64];
    __shared__ unsigned short Bs[2][128 * 64];

    const int t    = threadIdx.x;
    const int wave = t >> 6;
    const int lane = t & 63;
    const int xcd  = b2 & 7;
    const int jj   = b2 >> 3;                     // 0..127
    const int n0   = (jj & 7) * 128;
    const int m0   = (xcd * 16 + (jj >> 3)) * 128;
    const int wr   = (wave >> 1) * 64;
    const int wc   = (wave & 1) * 64;
    const int lm   = lane & 15;
    const int quad = lane >> 4;

    int aoff[4], boff[4];
#pragma unroll
    for (int i = 0; i < 4; i++) {
        const int slot = wave * 256 + i * 64 + lane;
        const int r = slot >> 3;
        const int csrc = (slot & 7) ^ (r & 7);
        aoff[i] = (m0 + r) * K + csrc * 8;
        boff[i] = (n0 + r) * K + csrc * 8;
    }

    auto STAGE = [&](int cb, int k0) {
#pragma unroll
        for (int i = 0; i < 4; i++) {
            __builtin_amdgcn_global_load_lds(
                (const __attribute__((address_space(1))) unsigned int*)(A + aoff[i] + k0),
                (__attribute__((address_space(3))) unsigned int*)((char*)&As[cb][0] + wave * 4096 + i * 1024),
                16, 0, 0);
            __builtin_amdgcn_global_load_lds(
                (const __attribute__((address_space(1))) unsigned int*)(W + boff[i] + k0),
                (__attribute__((address_space(3))) unsigned int*)((char*)&Bs[cb][0] + wave * 4096 + i * 1024),
                16, 0, 0);
        }
    };

    f32x4 acc[4][4] = {};

    STAGE(0, 0);
    __syncthreads();   // buf0 ready

    int cur = 0;
    for (int k0 = 0; k0 < K; k0 += 64) {
        if (k0 + 64 < K) STAGE(cur ^ 1, k0 + 64);   // prefetch next tile

        bf16x8 af[2][4], bfr[2][4];
#pragma unroll
        for (int ks = 0; ks < 2; ks++)
#pragma unroll
            for (int i = 0; i < 4; i++) {
                const int pos = ((ks * 4 + quad) ^ (lm & 7)) * 16;
                af[ks][i]  = *(const bf16x8*)((const char*)&As[cur][0] + (wr + i * 16 + lm) * 128 + pos);
                bfr[ks][i] = *(const bf16x8*)((const char*)&Bs[cur][0] + (wc + i * 16 + lm) * 128 + pos);
            }
        __builtin_amdgcn_s_setprio(1);
#pragma unroll
        for (int ks = 0; ks < 2; ks++)
#pragma unroll
            for (int i = 0; i < 4; i++)
#pragma unroll
                for (int j = 0; j < 4; j++)
                    acc[i][j] = __builtin_amdgcn_mfma_f32_16x16x32_bf16(af[ks][i], bfr[ks][j],
                                                                        acc[i][j], 0, 0, 0);
        __builtin_amdgcn_s_setprio(0);
        __syncthreads();   // reads done + next stage drained
        cur ^= 1;
    }

    const int outm = (OUTM_CONST >= 0) ? OUTM_CONST : outm_rt;

#pragma unroll
    for (int i = 0; i < 4; i++) {
        const int row = m0 + wr + i * 16 + quad * 4;
#pragma unroll
        for (int j = 0; j < 4; j++) {
            const int col = n0 + wc + j * 16 + lm;
            const float bb = bias[col];
            if (outm == 2) {
                const int bi = row >> 10, n2 = row & 1023;
                const int hh = col >> 6, dh = col & 63;
                uint2 pkd;
                pkd.x = pk2((acc[i][j][0] + bb) * scale, (acc[i][j][1] + bb) * scale);
                pkd.y = pk2((acc[i][j][2] + bb) * scale, (acc[i][j][3] + bb) * scale);
                *(uint2*)&((unsigned short*)Cp)[((size_t)((bi * 16 + hh) * 64 + dh) << 10) + n2] = pkd;
            } else if (outm == 0) {
#pragma unroll
                for (int rr = 0; rr < 4; rr++)
                    ((unsigned short*)Cp)[(size_t)(row + rr) * N + col] =
                        f2bf((acc[i][j][rr] + bb) * scale);
            } else {
#pragma unroll
                for (int rr = 0; rr < 4; rr++)
                    ((float*)Cp)[(size_t)(row + rr) * N + col] = (acc[i][j][rr] + bb) * scale;
            }
        }
    }
}

// Fused Q/K/V projection GEMM: grid 3072, z = bid>>10 selects the GEMM.
__global__ __launch_bounds__(256, 2) void gemm_qkv(const unsigned short* __restrict__ qb,
                                                   const unsigned short* __restrict__ xb,
                                                   const unsigned short* __restrict__ Wqb,
                                                   const unsigned short* __restrict__ Wkb,
                                                   const unsigned short* __restrict__ Wvb,
                                                   const float* __restrict__ bq,
                                                   const float* __restrict__ bk,
                                                   const float* __restrict__ bv,
                                                   unsigned short* __restrict__ Qo,
                                                   unsigned short* __restrict__ Ko,
                                                   unsigned short* __restrict__ Vo) {
    const int bid = blockIdx.x;
    const int z   = bid >> 10;          // 0=Q 1=K 2=V (wave-uniform)
    const int b2  = bid & 1023;
    const unsigned short* A = (z == 0) ? qb : xb;
    const unsigned short* W = (z == 0) ? Wqb : (z == 1) ? Wkb : Wvb;
    const float* bias       = (z == 0) ? bq : (z == 1) ? bk : bv;
    void* Cp                = (z == 0) ? (void*)Qo : (z == 1) ? (void*)Ko : (void*)Vo;
    const float scale       = (z == 0) ? QSCALE : 1.0f;
    gemm_body<-1>(A, W, bias, Cp, scale, b2, (z == 2) ? 2 : 0);
}

// Single GEMM (O-projection): grid 1024.
template <int OUTM>
__global__ __launch_bounds__(256, 2) void gemm2(const unsigned short* __restrict__ A,
                                                const unsigned short* __restrict__ W,
                                                const float* __restrict__ bias,
                                                void* __restrict__ Cp,
                                                float scale) {
    gemm_body<OUTM>(A, W, bias, Cp, scale, blockIdx.x, OUTM);
}

// ---------------------------------------------------------------------------
// Fallback GEMM (fp32 inputs, conversion in staging) — minimal-ws path only.
// ---------------------------------------------------------------------------
template <bool A_BF16, int OUTM>
__global__ __launch_bounds__(256) void gemm_bt(const void* __restrict__ Ap,
                                               const float* __restrict__ Wp,
                                               const float* __restrict__ bias,
                                               void* __restrict__ Cp,
                                               float scale) {
    constexpr int N = 1024, K = 1024;
    __shared__ unsigned short As[128 * 40];
    __shared__ unsigned short Bs[128 * 40];

    const int t    = threadIdx.x;
    const int n0   = blockIdx.x * 128;
    const int m0   = blockIdx.y * 128;
    const int wave = t >> 6;
    const int lane = t & 63;
    const int wr   = (wave >> 1) * 64;
    const int wc   = (wave & 1) * 64;
    const int lm   = lane & 15;
    const int quad = lane >> 4;
    const int kfr  = quad * 8;
    const int srow  = t >> 1;
    const int shalf = (t & 1) * 16;

    f32x4 acc[4][4] = {};

    for (int k0 = 0; k0 < K; k0 += 32) {
        {
            unsigned short* dst = &As[srow * 40 + shalf];
            if constexpr (A_BF16) {
                const unsigned short* pa =
                    (const unsigned short*)Ap + (size_t)(m0 + srow) * K + k0 + shalf;
                *(uint4*)dst       = *(const uint4*)pa;
                *(uint4*)(dst + 8) = *(const uint4*)(pa + 8);
            } else {
                const float* pa = (const float*)Ap + (size_t)(m0 + srow) * K + k0 + shalf;
                float4 f0 = *(const float4*)(pa + 0);
                float4 f1 = *(const float4*)(pa + 4);
                float4 f2 = *(const float4*)(pa + 8);
                float4 f3 = *(const float4*)(pa + 12);
                uint4 u0, u1;
                u0.x = pk2(f0.x, f0.y); u0.y = pk2(f0.z, f0.w);
                u0.z = pk2(f1.x, f1.y); u0.w = pk2(f1.z, f1.w);
                u1.x = pk2(f2.x, f2.y); u1.y = pk2(f2.z, f2.w);
                u1.z = pk2(f3.x, f3.y); u1.w = pk2(f3.z, f3.w);
                *(uint4*)dst       = u0;
                *(uint4*)(dst + 8) = u1;
            }
        }
        {
            const float* pb = Wp + (size_t)(n0 + srow) * K + k0 + shalf;
            float4 f0 = *(const float4*)(pb + 0);
            float4 f1 = *(const float4*)(pb + 4);
            float4 f2 = *(const float4*)(pb + 8);
            float4 f3 = *(const float4*)(pb + 12);
            uint4 u0, u1;
            u0.x = pk2(f0.x, f0.y); u0.y = pk2(f0.z, f0.w);
            u0.z = pk2(f1.x, f1.y); u0.w = pk2(f1.z, f1.w);
            u1.x = pk2(f2.x, f2.y); u1.y = pk2(f2.z, f2.w);
            u1.z = pk2(f3.x, f3.y); u1.w = pk2(f3.z, f3.w);
            unsigned short* dst = &Bs[srow * 40 + shalf];
            *(uint4*)dst       = u0;
            *(uint4*)(dst + 8) = u1;
        }
        __syncthreads();

        bf16x8 af[4], bfr[4];
#pragma unroll
        for (int i = 0; i < 4; i++)
            af[i] = *reinterpret_cast<const bf16x8*>(&As[(wr + i * 16 + lm) * 40 + kfr]);
#pragma unroll
        for (int j = 0; j < 4; j++)
            bfr[j] = *reinterpret_cast<const bf16x8*>(&Bs[(wc + j * 16 + lm) * 40 + kfr]);
#pragma unroll
        for (int i = 0; i < 4; i++)
#pragma unroll
            for (int j = 0; j < 4; j++)
                acc[i][j] = __builtin_amdgcn_mfma_f32_16x16x32_bf16(af[i], bfr[j],
                                                                    acc[i][j], 0, 0, 0);
        __syncthreads();
    }

#pragma unroll
    for (int i = 0; i < 4; i++) {
        const int row = m0 + wr + i * 16 + quad * 4;
#pragma unroll
        for (int j = 0; j < 4; j++) {
            const int col = n0 + wc + j * 16 + lm;
            const float bb = bias[col];
#pragma unroll
            for (int rr = 0; rr < 4; rr++) {
                const float v = (acc[i][j][rr] + bb) * scale;
                const int m = row + rr;
                if constexpr (OUTM == 0) {
                    ((unsigned short*)Cp)[(size_t)m * N + col] = f2bf(v);
                } else if constexpr (OUTM == 1) {
                    ((float*)Cp)[(size_t)m * N + col] = v;
                } else {
                    const int bi = m >> 10, n2 = m & 1023;
                    const int hh = col >> 6, dh = col & 63;
                    ((unsigned short*)Cp)[((size_t)((bi * 16 + hh) * 64 + dh) << 10) + n2] =
                        f2bf(v);
                }
            }
        }
    }
}

// ---------------------------------------------------------------------------
// Pack adj (int32 0/1, [1024][1024]) into bitmask [1024][32] words.
// ---------------------------------------------------------------------------
__global__ __launch_bounds__(256) void pack_adj(const int* __restrict__ adj,
                                                unsigned* __restrict__ adjm) {
    const int idx = blockIdx.x * 256 + threadIdx.x;  // 0..32767
    const int* src = adj + (size_t)idx * 32;
    unsigned w = 0;
#pragma unroll
    for (int i = 0; i < 32; i++) w |= (src[i] != 0 ? 1u : 0u) << i;
    adjm[idx] = w;
}

// ---------------------------------------------------------------------------
// MFMA flash attention, 32x32x16 shape, swapped QK^T, in-register softmax.
// 1D grid 2048 (XCD-swizzled), 4 waves x 32 q-rows = 128 q per block. (R7)
// ---------------------------------------------------------------------------
__global__ __launch_bounds__(256, 3) void attn_kernel(const unsigned short* __restrict__ Q,
                                                      const unsigned short* __restrict__ K,
                                                      const unsigned short* __restrict__ Vt,
                                                      const unsigned* __restrict__ adjm,
                                                      unsigned short* __restrict__ O) {
    __shared__ unsigned short Kbuf[2][4096];   // [kv 0..63][8-chunk pos 0..7]
    __shared__ unsigned short Vbuf[2][4096];   // [dh 0..63][pos]

    const int t    = threadIdx.x;
    const int wave = t >> 6;
    const int lane = t & 63;
    const int l32  = lane & 31;
    const int hi   = lane >> 5;

    const int bid   = blockIdx.x;
    const int xcd   = bid & 7;
    const int jj    = bid >> 3;               // 0..255
    const int group = xcd * 32 + (jj >> 3);   // 0..255 = b*16+h
    const int q0    = (jj & 7) * 128;
    const int h     = group & 15;
    const int b     = group >> 4;

    const int qrow = q0 + wave * 32 + l32;    // this lane's q row

    int    ldofs[2];
    size_t kofs[2], vofs[2];
#pragma unroll
    for (int i = 0; i < 2; i++) {
        const int slot = i * 256 + t;
        const int r    = slot >> 3;
        const int cs   = (slot & 7) ^ (r & 7);
        ldofs[i] = slot * 16;
        kofs[i]  = (size_t)(b * 1024 + r) * 1024 + h * 64 + cs * 8;   // + j0*1024
        vofs[i]  = ((size_t)((b * 16 + h) * 64 + r) << 10) + cs * 8;  // + j0
    }

    // Q B-frags: aq[s] covers dh = s*16 + hi*8 .. +8 for col q = l32.
    bf16x8 aq[4];
    {
        const unsigned short* qp =
            Q + ((size_t)(b * 1024 + qrow) * 1024 + h * 64 + hi * 8);
#pragma unroll
        for (int s = 0; s < 4; s++)
            aq[s] = __builtin_bit_cast(bf16x8, *(const uint4*)(qp + s * 16));
    }

    bf16x8 bones;
    {
        uint4 u; u.x = 0x3F803F80u; u.y = u.x; u.z = u.x; u.w = u.x;
        bones = __builtin_bit_cast(bf16x8, u);   // all-ones B fragment
    }

    f32x16 of0 = {}, of1 = {}, ol = {};

    auto STAGE = [&](int bi, int c) {
        const size_t j0 = (size_t)c * 64;
#pragma unroll
        for (int i = 0; i < 2; i++) {
            __builtin_amdgcn_global_load_lds(
                (const __attribute__((address_space(1))) unsigned int*)(K + kofs[i] + j0 * 1024),
                (__attribute__((address_space(3))) unsigned int*)((char*)&Kbuf[bi][0] + ldofs[i]),
                16, 0, 0);
            __builtin_amdgcn_global_load_lds(
                (const __attribute__((address_space(1))) unsigned int*)(Vt + vofs[i] + j0),
                (__attribute__((address_space(3))) unsigned int*)((char*)&Vbuf[bi][0] + ldofs[i]),
                16, 0, 0);
        }
    };

    STAGE(0, 0);
    __syncthreads();   // vmcnt(0) drain: buf0 ready

    int bi = 0;
    for (int c = 0; c < 16; ++c) {
        const uint2 mw = *(const uint2*)&adjm[(size_t)qrow * 32 + c * 2];

        if (c < 15) STAGE(bi ^ 1, c + 1);

        // --- QK^T (swapped): sf[f] over dh steps ---
        f32x16 sf[2] = {{}, {}};
        __builtin_amdgcn_s_setprio(1);
#pragma unroll
        for (int f = 0; f < 2; f++)
#pragma unroll
            for (int s = 0; s < 4; s++) {
                const int pos = ((2 * s + hi) ^ (l32 & 7)) * 16;
                const bf16x8 kf =
                    *(const bf16x8*)((const char*)&Kbuf[bi][0] + (f * 32 + l32) * 128 + pos);
                sf[f] = __builtin_amdgcn_mfma_f32_32x32x16_bf16(kf, aq[s], sf[f], 0, 0, 0);
            }
        __builtin_amdgcn_s_setprio(0);

        // --- mask + exp2 + pack to bf16 pairs (in registers) ---
        unsigned d[2][4][2];
#pragma unroll
        for (int f = 0; f < 2; f++) {
            const unsigned wh = ((f == 0) ? mw.x : mw.y) >> (hi * 4);
            float p[16];
#pragma unroll
            for (int r = 0; r < 16; r++) {
                const unsigned bit = (wh >> ((r & 3) + 8 * (r >> 2))) & 1u;
                p[r] = __builtin_amdgcn_exp2f(bit ? sf[f][r] : -1e30f);
            }
#pragma unroll
            for (int a = 0; a < 4; a++)
#pragma unroll
                for (int bb = 0; bb < 2; bb++) {
                    unsigned dd;
                    asm("v_cvt_pk_bf16_f32 %0, %1, %2"
                        : "=v"(dd) : "v"(p[4 * a + 2 * bb]), "v"(p[4 * a + 2 * bb + 1]));
                    d[f][a][bb] = dd;
                }
        }

        // --- redistribute halves: build PV A-frags tA[s] (kv = s*16+hi*8+j) ---
        bf16x8 tA[4];
#pragma unroll
        for (int s = 0; s < 4; s++) {
            const int f = s >> 1, sg = s & 1;
            unsigned A0 = d[f][2 * sg][0], B0 = d[f][2 * sg + 1][0];
            unsigned A1 = d[f][2 * sg][1], B1 = d[f][2 * sg + 1][1];
            asm("v_permlane32_swap_b32 %0, %1" : "+v"(A0), "+v"(B0));
            asm("v_permlane32_swap_b32 %0, %1" : "+v"(A1), "+v"(B1));
            uint4 td; td.x = A0; td.y = A1; td.z = B0; td.w = B1;
            tA[s] = __builtin_bit_cast(bf16x8, td);
        }

        // --- PV + row-sum ---
        __builtin_amdgcn_s_setprio(1);
#pragma unroll
        for (int s = 0; s < 4; s++) {
            const int pos = ((2 * s + hi) ^ (l32 & 7)) * 16;
            const bf16x8 v0 = *(const bf16x8*)((const char*)&Vbuf[bi][0] + l32 * 128 + pos);
            const bf16x8 v1 = *(const bf16x8*)((const char*)&Vbuf[bi][0] + (32 + l32) * 128 + pos);
            of0 = __builtin_amdgcn_mfma_f32_32x32x16_bf16(tA[s], v0, of0, 0, 0, 0);
            of1 = __builtin_amdgcn_mfma_f32_32x32x16_bf16(tA[s], v1, of1, 0, 0, 0);
            ol  = __builtin_amdgcn_mfma_f32_32x32x16_bf16(tA[s], bones, ol, 0, 0, 0);
        }
        __builtin_amdgcn_s_setprio(0);

        __syncthreads();   // drain: next buf staged + all waves done reading bi
        bi ^= 1;
    }

    // --- normalize + store: lane holds q rows crow(r,hi), d = e*32 + l32 ---
#pragma unroll
    for (int r = 0; r < 16; r++) {
        const float iv = 1.0f / ol[r];
        const size_t row = (size_t)(b * 1024 + q0 + wave * 32 +
                                    (r & 3) + 8 * (r >> 2) + 4 * hi);
        unsigned short* op = O + row * 1024 + h * 64 + l32;
        op[0]  = f2bf(of0[r] * iv);
        op[32] = f2bf(of1[r] * iv);
    }
}

// ---------------------------------------------------------------------------
extern "C" void kernel_launch(void* const* d_in, const int* in_sizes, int n_in,
                              void* d_out, int out_size, void* d_ws, size_t ws_size,
                              hipStream_t stream) {
    const float* q  = (const float*)d_in[0];
    const float* x  = (const float*)d_in[1];
    const float* Wq = (const float*)d_in[2];
    const float* bq = (const float*)d_in[3];
    const float* Wk = (const float*)d_in[4];
    const float* bk = (const float*)d_in[5];
    const float* Wv = (const float*)d_in[6];
    const float* bv = (const float*)d_in[7];
    const float* Wo = (const float*)d_in[8];
    const float* bo = (const float*)d_in[9];
    const int* adj  = (const int*)d_in[10];
    float* out = (float*)d_out;

    const size_t MB = 1024 * 1024;
    char* w = (char*)d_ws;

    dim3 tb(256);
    const size_t FULL_WS = 168 * MB + 128 * 1024;

    if (ws_size >= FULL_WS) {
        unsigned short* qb  = (unsigned short*)(w);
        unsigned short* xb  = (unsigned short*)(w + 32 * MB);
        unsigned short* Wqb = (unsigned short*)(w + 64 * MB);
        unsigned short* Wkb = (unsigned short*)(w + 66 * MB);
        unsigned short* Wvb = (unsigned short*)(w + 68 * MB);
        unsigned short* Wob = (unsigned short*)(w + 70 * MB);
        unsigned short* Qb  = (unsigned short*)(w + 72 * MB);
        unsigned short* Kb  = (unsigned short*)(w + 104 * MB);
        unsigned short* Vtb = (unsigned short*)(w + 136 * MB);
        unsigned* adjm      = (unsigned*)(w + 168 * MB);
        unsigned short* Ob  = qb;  // qb dead after fused QKV GEMM

        hipLaunchKernelGGL(cvt_bf16, dim3(8192, 2), tb, 0, stream, q, qb, x, xb);
        hipLaunchKernelGGL(cvt_w4, dim3(512, 4), tb, 0, stream, Wq, Wk, Wv, Wo,
                           Wqb, Wkb, Wvb, Wob);
        hipLaunchKernelGGL(pack_adj, dim3(128), tb, 0, stream, adj, adjm);

        hipLaunchKernelGGL(gemm_qkv, dim3(3072), tb, 0, stream,
                           qb, xb, Wqb, Wkb, Wvb, bq, bk, bv, Qb, Kb, Vtb);
        hipLaunchKernelGGL(attn_kernel, dim3(2048), tb, 0, stream, Qb, Kb, Vtb, adjm, Ob);
        hipLaunchKernelGGL((gemm2<1>), dim3(1024), tb, 0, stream, Ob, Wob, bo, (void*)out, 1.0f);
    } else {
        // minimal path (134.1 MB): convert in GEMM staging
        unsigned short* Qb  = (unsigned short*)(w);
        unsigned short* Kb  = (unsigned short*)(w + 32 * MB);
        unsigned short* Vtb = (unsigned short*)(w + 64 * MB);
        unsigned short* Ob  = (unsigned short*)(w + 96 * MB);
        unsigned* adjm      = (unsigned*)(w + 128 * MB);

        hipLaunchKernelGGL(pack_adj, dim3(128), tb, 0, stream, adj, adjm);
        hipLaunchKernelGGL((gemm_bt<false, 0>), dim3(8, 128), tb, 0, stream,
                           (const void*)q, Wq, bq, (void*)Qb, QSCALE);
        hipLaunchKernelGGL((gemm_bt<false, 0>), dim3(8, 128), tb, 0, stream,
                           (const void*)x, Wk, bk, (void*)Kb, 1.0f);
        hipLaunchKernelGGL((gemm_bt<false, 2>), dim3(8, 128), tb, 0, stream,
                           (const void*)x, Wv, bv, (void*)Vtb, 1.0f);
        hipLaunchKernelGGL(attn_kernel, dim3(2048), tb, 0, stream, Qb, Kb, Vtb, adjm, Ob);
        hipLaunchKernelGGL((gemm_bt<true, 1>), dim3(8, 128), tb, 0, stream,
                           (const void*)Ob, Wo, bo, (void*)out, 1.0f);
    }
}